// Round 5
// baseline (335.450 us; speedup 1.0000x reference)
//
#include <hip/hip_runtime.h>

#define NS 10

typedef __attribute__((ext_vector_type(8))) short bf16x8;
typedef __attribute__((ext_vector_type(4))) float f32x4;

__device__ __forceinline__ float bf2f(unsigned short u) {
  union { unsigned int i; float f; } x;
  x.i = ((unsigned int)u) << 16;
  return x.f;
}
__device__ __forceinline__ unsigned short f2bf(float f) {
  union { float f; unsigned int i; } x; x.f = f;
  unsigned int r = x.i + 0x7FFFu + ((x.i >> 16) & 1u);
  return (unsigned short)(r >> 16);
}
__device__ __forceinline__ unsigned pk2(float a, float b) {
  return (unsigned)f2bf(a) | ((unsigned)f2bf(b) << 16);
}

// ============ prep: weight pack (fp32 [K][N] -> bf16 [N][K]) + eg0 gather ===
// wt1: [mp*2+l][256][576] (cols: Ws | Wn | Wedge); wte: [mp][64][576]
// eg0: [2][5120][64] bf16 = emb[mp][e0]
#define PACKB 2592  // (2*2*256*576 + 2*64*576) / 256
__global__ __launch_bounds__(256) void prep_k(
    const float* __restrict__ Wself, const float* __restrict__ Wneigh,
    const float* __restrict__ Wedg, const float* __restrict__ Wec,
    unsigned short* __restrict__ wt1, unsigned short* __restrict__ wte,
    const float* __restrict__ emb0, const float* __restrict__ emb1,
    const int* __restrict__ e0a, const int* __restrict__ e0b,
    unsigned short* __restrict__ eg0) {
  int b = blockIdx.x;
  if (b < PACKB) {
    int t = b * 256 + threadIdx.x;
    const int total1 = 2 * 2 * 256 * 576;
    if (t < total1) {
      int g = t / 147456, r = t - g * 147456;
      int n = r / 576, k = r - n * 576;
      float v;
      if (k < 256) v = Wself[(long)g * 65536 + k * 256 + n];
      else if (k < 512) v = Wneigh[(long)g * 65536 + (k - 256) * 256 + n];
      else v = Wedg[(long)g * 16384 + (k - 512) * 256 + n];
      wt1[t] = f2bf(v);
    } else {
      int t2 = t - total1;  // < 2*64*576
      int mp = t2 / 36864, r = t2 - mp * 36864;
      int n = r / 576, k = r - n * 576;
      wte[t2] = f2bf(Wec[(long)(mp * 2) * 36864 + k * 64 + n]);
    }
  } else {
    int b2 = b - PACKB;          // 0..639
    int mp = b2 / 320;
    int t = (b2 - mp * 320) * 256 + threadIdx.x;  // < 5120*16
    int m = t >> 4, d4 = t & 15;
    const float* tb = mp ? emb1 : emb0;
    const int* ei = mp ? e0b : e0a;
    long r = ei[m];
    float4 v = *(const float4*)(tb + r * 64 + d4 * 4);
    uint2 o; o.x = pk2(v.x, v.y); o.y = pk2(v.z, v.w);
    *(uint2*)(eg0 + (long)mp * 327680 + (long)m * 64 + d4 * 4) = o;
  }
}

// ================= mean-over-NS-rows kernel (bf16 in/out) ===================
struct GJob {
  const unsigned short* table; unsigned short* out;
  int M, D4, ostride, blk0;
};
struct GJobs { GJob j[4]; };

__global__ __launch_bounds__(256) void mean_k(GJobs js, int njobs) {
  int b = blockIdx.x, ji = 0;
  for (int k = 1; k < njobs; ++k) if (b >= js.j[k].blk0) ji = k;
  GJob jb = js.j[ji];
  int t = (b - jb.blk0) * 256 + threadIdx.x;
  if (t >= jb.M * jb.D4) return;
  int m = t / jb.D4, d4 = t - m * jb.D4;
  long D = (long)jb.D4 * 4;
  float ax = 0.f, ay = 0.f, az = 0.f, aw = 0.f;
  for (int s = 0; s < NS; ++s) {
    long r = (long)m * NS + s;
    uint2 v = *(const uint2*)(jb.table + r * D + d4 * 4);
    ax += bf2f((unsigned short)(v.x & 0xFFFF)); ay += bf2f((unsigned short)(v.x >> 16));
    az += bf2f((unsigned short)(v.y & 0xFFFF)); aw += bf2f((unsigned short)(v.y >> 16));
  }
  uint2 o; o.x = pk2(ax * 0.1f, ay * 0.1f); o.y = pk2(az * 0.1f, aw * 0.1f);
  *(uint2*)(jb.out + (long)m * jb.ostride + d4 * 4) = o;
}

// ======= GEMM1 fused: h01 = relu([gather|neigh-mean|edge-mean] @ Wt^T) ======
// BM=128, BN=256 (grid.x = m-tile, grid.y = mp), K = 256+256+64.
// A rows gathered on the fly from fp32 feats/emb with per-row index registers.
__global__ __launch_bounds__(256) void gemm1_fused_k(
    const float* __restrict__ feats, const float* __restrict__ emb0,
    const float* __restrict__ emb1, const int* __restrict__ ids,
    const int* __restrict__ n0a, const int* __restrict__ n0b,
    const int* __restrict__ n1a, const int* __restrict__ n1b,
    const int* __restrict__ e0a, const int* __restrict__ e0b,
    const int* __restrict__ e1a, const int* __restrict__ e1b,
    const unsigned short* __restrict__ wt1, unsigned short* __restrict__ h01) {
  __shared__ unsigned short As[128 * 40];
  __shared__ unsigned short Bs[256 * 40];
  int tid = threadIdx.x;
  int m0 = blockIdx.x * 128, mp = blockIdx.y;
  const float* emb = mp ? emb1 : emb0;
  const int* n0 = mp ? n0b : n0a;
  const int* n1 = mp ? n1b : n1a;
  const int* e0 = mp ? e0b : e0a;
  const int* e1 = mp ? e1b : e1a;
  const unsigned short* Bp = wt1 + (long)(mp * 2) * 147456;

  // per-thread row indices (row = tid>>1, fixed across K loop)
  int row = tid >> 1, half = tid & 1;
  int gr = m0 + row;
  bool lvl0 = (m0 < 512);  // uniform per block (512 = 4*128)
  int i_self = lvl0 ? ids[gr] : n0[gr - 512];
  const int* nbp = lvl0 ? (n0 + gr * NS) : (n1 + (gr - 512) * NS);
  const int* ebp = lvl0 ? (e0 + gr * NS) : (e1 + (gr - 512) * NS);
  int nb[NS];
#pragma unroll
  for (int s = 0; s < NS; ++s) nb[s] = nbp[s];

  f32x4 acc[4][8];
#pragma unroll
  for (int i = 0; i < 4; ++i)
#pragma unroll
    for (int j = 0; j < 8; ++j) acc[i][j] = (f32x4){0.f, 0.f, 0.f, 0.f};

  int wave = tid >> 6, lane = tid & 63;
  int wm = wave >> 1, wn = wave & 1;
  int quad = lane >> 4, r16 = lane & 15;

  for (int it = 0; it < 18; ++it) {
    // ---- A stage (gather fused): 16 fp32 -> 16 bf16 in LDS
    {
      float vv[16];
      if (it < 8) {            // self feats, k0 = it*32
        const float* p = feats + (long)i_self * 256 + it * 32 + half * 16;
#pragma unroll
        for (int q = 0; q < 4; ++q) {
          float4 v = *(const float4*)(p + q * 4);
          vv[q * 4] = v.x; vv[q * 4 + 1] = v.y; vv[q * 4 + 2] = v.z; vv[q * 4 + 3] = v.w;
        }
      } else if (it < 16) {    // neighbor mean, k0 = (it-8)*32
#pragma unroll
        for (int q = 0; q < 16; ++q) vv[q] = 0.f;
        int k0 = (it - 8) * 32;
        for (int s = 0; s < NS; ++s) {
          const float* p = feats + (long)nb[s] * 256 + k0 + half * 16;
#pragma unroll
          for (int q = 0; q < 4; ++q) {
            float4 v = *(const float4*)(p + q * 4);
            vv[q * 4] += v.x; vv[q * 4 + 1] += v.y; vv[q * 4 + 2] += v.z; vv[q * 4 + 3] += v.w;
          }
        }
#pragma unroll
        for (int q = 0; q < 16; ++q) vv[q] *= 0.1f;
      } else {                 // edge mean, k0 = (it-16)*32
#pragma unroll
        for (int q = 0; q < 16; ++q) vv[q] = 0.f;
        int k0 = (it - 16) * 32;
        for (int s = 0; s < NS; ++s) {
          const float* p = emb + (long)ebp[s] * 64 + k0 + half * 16;
#pragma unroll
          for (int q = 0; q < 4; ++q) {
            float4 v = *(const float4*)(p + q * 4);
            vv[q * 4] += v.x; vv[q * 4 + 1] += v.y; vv[q * 4 + 2] += v.z; vv[q * 4 + 3] += v.w;
          }
        }
#pragma unroll
        for (int q = 0; q < 16; ++q) vv[q] *= 0.1f;
      }
      uint4 w0 = {pk2(vv[0], vv[1]), pk2(vv[2], vv[3]), pk2(vv[4], vv[5]), pk2(vv[6], vv[7])};
      uint4 w1 = {pk2(vv[8], vv[9]), pk2(vv[10], vv[11]), pk2(vv[12], vv[13]), pk2(vv[14], vv[15])};
      int off = row * 40 + half * 16;
      *(uint4*)&As[off] = w0;
      *(uint4*)&As[off + 8] = w1;
    }
    // ---- B stage: 256 cols x 32 k (k = it*32 in packed [col][576])
    {
      int kk = it * 32;
#pragma unroll
      for (int l = 0; l < 2; ++l) {
        int col = (tid >> 1) + l * 128;
        const unsigned short* p = Bp + (long)col * 576 + kk + half * 16;
        uint4 b0 = *(const uint4*)p;
        uint4 b1 = *(const uint4*)(p + 8);
        int off = col * 40 + half * 16;
        *(uint4*)&Bs[off] = b0;
        *(uint4*)&Bs[off + 8] = b1;
      }
    }
    __syncthreads();
    bf16x8 af[4];
#pragma unroll
    for (int i = 0; i < 4; ++i)
      af[i] = *(const bf16x8*)&As[(wm * 64 + i * 16 + r16) * 40 + quad * 8];
    bf16x8 bfr[8];
#pragma unroll
    for (int j = 0; j < 8; ++j)
      bfr[j] = *(const bf16x8*)&Bs[(wn * 128 + j * 16 + r16) * 40 + quad * 8];
#pragma unroll
    for (int i = 0; i < 4; ++i)
#pragma unroll
      for (int j = 0; j < 8; ++j)
        acc[i][j] = __builtin_amdgcn_mfma_f32_16x16x32_bf16(af[i], bfr[j], acc[i][j], 0, 0, 0);
    __syncthreads();
  }
  // ---- epilogue: relu -> bf16
  unsigned short* Cp = h01 + (long)mp * 5632 * 256;
#pragma unroll
  for (int i = 0; i < 4; ++i) {
#pragma unroll
    for (int j = 0; j < 8; ++j) {
#pragma unroll
      for (int r = 0; r < 4; ++r) {
        int rr = m0 + wm * 64 + i * 16 + quad * 4 + r;
        int cc = wn * 128 + j * 16 + r16;
        float v = fmaxf(acc[i][j][r], 0.f);
        Cp[(long)rr * 256 + cc] = f2bf(v);
      }
    }
  }
}

// ================= generic MFMA GEMM (GEMM2 / GEMM3) ========================
template<int BN, int ACT, bool BIAS, bool OUTBF>  // ACT: 0 none, 2 tanh
__global__ __launch_bounds__(256) void gemm_mfma_k(
    const unsigned short* A0, long as0, int K0, int dv0,
    const unsigned short* A1, long as1, int K1, int dv1,
    const unsigned short* A2, long as2, int K2, int dv2,
    const unsigned short* Bt, long bs, int Ktot,
    const float* bias, long biass,
    void* Cv, long cs, int N) {
  constexpr int TN = BN / 32;
  __shared__ unsigned short As[128 * 40];
  __shared__ unsigned short Bs[BN * 40];
  int tid = threadIdx.x;
  int mp = blockIdx.z;
  int n0 = blockIdx.x * BN, m0 = blockIdx.y * 128;
  const unsigned short* Bp = Bt + (long)mp * bs;

  f32x4 acc[4][TN];
#pragma unroll
  for (int i = 0; i < 4; ++i)
#pragma unroll
    for (int j = 0; j < TN; ++j) acc[i][j] = (f32x4){0.f, 0.f, 0.f, 0.f};

  const unsigned short* Asg[3] = {A0 + (long)mp * as0, A1 + (long)mp * as1,
                                  A2 + (long)mp * as2};
  const int Ksg[3] = {K0, K1, K2};
  const int Dsg[3] = {dv0, dv1, dv2};

  int wave = tid >> 6, lane = tid & 63;
  int wm = wave >> 1, wn = wave & 1;
  int quad = lane >> 4, r16 = lane & 15;

  int kbase = 0;
  for (int sg = 0; sg < 3; ++sg) {
    const unsigned short* A = Asg[sg];
    int K = Ksg[sg], dv = Dsg[sg];
    for (int k0 = 0; k0 < K; k0 += 32) {
      {
        int row = tid >> 1, half = tid & 1;
        int gr = m0 + row;
        int ar = (dv > 1) ? (gr / dv) : gr;
        const unsigned short* p = A + (long)ar * K + k0 + half * 16;
        uint4 v0 = *(const uint4*)p;
        uint4 v1 = *(const uint4*)(p + 8);
        int off = row * 40 + half * 16;
        *(uint4*)&As[off] = v0;
        *(uint4*)&As[off + 8] = v1;
      }
      if (BN == 128) {
        int col = tid >> 1, half = tid & 1;
        const unsigned short* p = Bp + (long)(n0 + col) * Ktot + kbase + k0 + half * 16;
        uint4 b0 = *(const uint4*)p;
        uint4 b1 = *(const uint4*)(p + 8);
        int off = col * 40 + half * 16;
        *(uint4*)&Bs[off] = b0;
        *(uint4*)&Bs[off + 8] = b1;
      } else {
        int col = tid >> 2, q = tid & 3;
        const unsigned short* p = Bp + (long)(n0 + col) * Ktot + kbase + k0 + q * 8;
        *(uint4*)&Bs[col * 40 + q * 8] = *(const uint4*)p;
      }
      __syncthreads();
      bf16x8 af[4];
#pragma unroll
      for (int i = 0; i < 4; ++i)
        af[i] = *(const bf16x8*)&As[(wm * 64 + i * 16 + r16) * 40 + quad * 8];
      bf16x8 bfr[TN];
#pragma unroll
      for (int j = 0; j < TN; ++j)
        bfr[j] = *(const bf16x8*)&Bs[(wn * (BN / 2) + j * 16 + r16) * 40 + quad * 8];
#pragma unroll
      for (int i = 0; i < 4; ++i)
#pragma unroll
        for (int j = 0; j < TN; ++j)
          acc[i][j] = __builtin_amdgcn_mfma_f32_16x16x32_bf16(af[i], bfr[j], acc[i][j], 0, 0, 0);
      __syncthreads();
    }
    kbase += K;
  }
#pragma unroll
  for (int i = 0; i < 4; ++i) {
#pragma unroll
    for (int j = 0; j < TN; ++j) {
#pragma unroll
      for (int r = 0; r < 4; ++r) {
        int row = m0 + wm * 64 + i * 16 + quad * 4 + r;
        int col = n0 + wn * (BN / 2) + j * 16 + r16;
        float v = acc[i][j][r];
        if (BIAS) v += bias[mp * biass + col];
        if (ACT == 2) v = tanhf(v);
        if (OUTBF)
          ((unsigned short*)Cv)[(long)mp * cs + (long)row * N + col] = f2bf(v);
        else
          ((float*)Cv)[(long)mp * cs + (long)row * N + col] = v;
      }
    }
  }
}

// ---- finalize: out = normalize((o0+o1)/2) @ fc_w + fc_b, f32 out ----
__global__ __launch_bounds__(64) void finalize_k(
    const float* __restrict__ o0, const float* __restrict__ o1,
    const float* __restrict__ fcw, const float* __restrict__ fcb,
    float* __restrict__ out) {
  int b = blockIdx.x, l = threadIdx.x;
  float v[4];
  float ss = 0.f;
#pragma unroll
  for (int k = 0; k < 4; ++k) {
    int j = l + 64 * k;
    v[k] = 0.5f * (o0[(long)b * 256 + j] + o1[(long)b * 256 + j]);
    ss += v[k] * v[k];
  }
#pragma unroll
  for (int off = 32; off > 0; off >>= 1) ss += __shfl_down(ss, off);
  ss = __shfl(ss, 0);
  float sc = 1.f / fmaxf(sqrtf(ss), 1e-12f);
  float p[8];
#pragma unroll
  for (int c = 0; c < 8; ++c) p[c] = 0.f;
#pragma unroll
  for (int k = 0; k < 4; ++k) {
    int j = l + 64 * k;
    float vh = v[k] * sc;
#pragma unroll
    for (int c = 0; c < 8; ++c) p[c] += vh * fcw[j * 8 + c];
  }
#pragma unroll
  for (int off = 32; off > 0; off >>= 1) {
#pragma unroll
    for (int c = 0; c < 8; ++c) p[c] += __shfl_down(p[c], off);
  }
  if (l == 0) {
#pragma unroll
    for (int c = 0; c < 8; ++c) out[b * 8 + c] = p[c] + fcb[c];
  }
}

extern "C" void kernel_launch(void* const* d_in, const int* in_sizes, int n_in,
                              void* d_out, int out_size, void* d_ws, size_t ws_size,
                              hipStream_t stream) {
  const int* ids = (const int*)d_in[0];
  const float* feats = (const float*)d_in[1];
  const int* n0a = (const int*)d_in[2];
  const int* n1a = (const int*)d_in[3];
  const int* n0b = (const int*)d_in[4];
  const int* n1b = (const int*)d_in[5];
  const int* e0a = (const int*)d_in[6];
  const int* e1a = (const int*)d_in[7];
  const int* e0b = (const int*)d_in[8];
  const int* e1b = (const int*)d_in[9];
  const float* emb0 = (const float*)d_in[10];
  const float* emb1 = (const float*)d_in[11];
  const float* Wself = (const float*)d_in[12];
  const float* Wneigh = (const float*)d_in[13];
  const float* Wedg = (const float*)d_in[14];
  const float* Wec = (const float*)d_in[15];
  const float* bec = (const float*)d_in[16];
  const float* fcw = (const float*)d_in[17];
  const float* fcb = (const float*)d_in[18];
  float* out = (float*)d_out;

  // ---- workspace ----
  float* osum = (float*)d_ws;                       // [2][512][256] f32
  unsigned short* eg0  = (unsigned short*)(osum + 262144);  // [2][5120][64]
  unsigned short* h01  = eg0 + 655360;              // [2][5632][256]
  unsigned short* enew = h01 + 2883584;             // [2][5120][64]
  unsigned short* h1m  = enew + 655360;             // [2][512][256]
  unsigned short* emn  = h1m + 262144;              // [2][512][64]
  unsigned short* wt1  = emn + 65536;               // [4][256][576]
  unsigned short* wte  = wt1 + 589824;              // [2][64][576]

  // 1) prep: pack weights + eg0 gather
  prep_k<<<dim3(PACKB + 640), dim3(256), 0, stream>>>(
      Wself, Wneigh, Wedg, Wec, wt1, wte, emb0, emb1, e0a, e0b, eg0);

  // 2) layer-0 agg with fused gather: h01 = relu(A1 @ WT1[mp][0])
  gemm1_fused_k<<<dim3(44, 2), dim3(256), 0, stream>>>(
      feats, emb0, emb1, ids, n0a, n0b, n1a, n1b, e0a, e0b, e1a, e1b, wt1, h01);

  // 3) edge update: enew = tanh([h0(rep10) | h1 | eg0] @ WTe + be) [2][5120][64]
  gemm_mfma_k<64, 2, true, true><<<dim3(1, 40, 2), dim3(256), 0, stream>>>(
      h01, 5632L * 256, 256, 10, h01 + 512 * 256, 5632L * 256, 256, 1,
      eg0, 5120L * 64, 64, 1,
      wte, 36864L, 576, bec, 128, enew, 5120L * 64, 64);

  // 4) means over S (h1m, emn)
  {
    GJobs gj; int blk = 0, nj = 0;
    auto add = [&](const unsigned short* table, unsigned short* o, int M, int D4,
                   int ostride) {
      gj.j[nj] = {table, o, M, D4, ostride, blk};
      blk += (M * D4) / 256; ++nj;
    };
    for (int mp = 0; mp < 2; ++mp) {
      add(h01 + (size_t)mp * 5632 * 256 + 512 * 256, h1m + (size_t)mp * 131072, 512, 64, 256);
      add(enew + (size_t)mp * 327680, emn + (size_t)mp * 32768, 512, 16, 64);
    }
    mean_k<<<dim3(blk), dim3(256), 0, stream>>>(gj, nj);
  }

  // 5) layer-1 agg: osum = [h0 | h1m | emn] @ WT1[mp][1]  [2][512][256] f32
  gemm_mfma_k<128, 0, false, false><<<dim3(2, 4, 2), dim3(256), 0, stream>>>(
      h01, 5632L * 256, 256, 1, h1m, 512L * 256, 256, 1, emn, 512L * 64, 64, 1,
      wt1 + 147456, 2L * 147456, 576, nullptr, 0, osum, 131072L, 256);

  // 6) metapath mean + L2 normalize + FC
  finalize_k<<<dim3(512), dim3(64), 0, stream>>>(osum, osum + 131072, fcw, fcb, out);
}

// Round 6
// 299.133 us; speedup vs baseline: 1.1214x; 1.1214x over previous
//
#include <hip/hip_runtime.h>

#define NS 10

typedef __attribute__((ext_vector_type(8))) short bf16x8;
typedef __attribute__((ext_vector_type(4))) float f32x4;

__device__ __forceinline__ float bf2f(unsigned short u) {
  union { unsigned int i; float f; } x;
  x.i = ((unsigned int)u) << 16;
  return x.f;
}
__device__ __forceinline__ unsigned short f2bf(float f) {
  union { float f; unsigned int i; } x; x.f = f;
  unsigned int r = x.i + 0x7FFFu + ((x.i >> 16) & 1u);
  return (unsigned short)(r >> 16);
}
__device__ __forceinline__ unsigned pk2(float a, float b) {
  return (unsigned)f2bf(a) | ((unsigned)f2bf(b) << 16);
}

// ===== gprep: weight pack (fp32 [K][N] -> bf16 [N][K]) + all input gathers ==
// wt1: [mp*2+l][256][576] (cols: Ws | Wn | Wedge); wte: [mp][64][576]
#define PACKB 2592  // (2*2*256*576 + 2*64*576) / 256
struct GJob {
  const float* table; const int* idx; unsigned short* out;
  int M, D4, ns, ostride, blk0; float inv;
};
struct GJobs { GJob j[14]; };

__global__ __launch_bounds__(256) void gprep_k(
    GJobs js, int njobs,
    const float* __restrict__ Wself, const float* __restrict__ Wneigh,
    const float* __restrict__ Wedg, const float* __restrict__ Wec,
    unsigned short* __restrict__ wt1, unsigned short* __restrict__ wte) {
  int b = blockIdx.x;
  if (b < PACKB) {
    int t = b * 256 + threadIdx.x;
    const int total1 = 2 * 2 * 256 * 576;
    if (t < total1) {
      int g = t / 147456, r = t - g * 147456;
      int n = r / 576, k = r - n * 576;
      float v;
      if (k < 256) v = Wself[(long)g * 65536 + k * 256 + n];
      else if (k < 512) v = Wneigh[(long)g * 65536 + (k - 256) * 256 + n];
      else v = Wedg[(long)g * 16384 + (k - 512) * 256 + n];
      wt1[t] = f2bf(v);
    } else {
      int t2 = t - total1;  // < 2*64*576
      int mp = t2 / 36864, r = t2 - mp * 36864;
      int n = r / 576, k = r - n * 576;
      wte[t2] = f2bf(Wec[(long)(mp * 2) * 36864 + k * 64 + n]);
    }
    return;
  }
  b -= PACKB;
  int ji = 0;
  for (int k = 1; k < njobs; ++k) if (b >= js.j[k].blk0) ji = k;
  GJob jb = js.j[ji];
  int t = (b - jb.blk0) * 256 + threadIdx.x;
  int m = t / jb.D4, d4 = t - m * jb.D4;
  long D = (long)jb.D4 * 4;
  float ax = 0.f, ay = 0.f, az = 0.f, aw = 0.f;
  for (int s = 0; s < jb.ns; ++s) {
    long r = jb.idx ? (long)jb.idx[(long)m * jb.ns + s] : ((long)m * jb.ns + s);
    float4 v = *(const float4*)(jb.table + r * D + d4 * 4);
    ax += v.x; ay += v.y; az += v.z; aw += v.w;
  }
  uint2 o; o.x = pk2(ax * jb.inv, ay * jb.inv); o.y = pk2(az * jb.inv, aw * jb.inv);
  *(uint2*)(jb.out + (long)m * jb.ostride + d4 * 4) = o;
}

// ============ GEMM1: BM=128, BN=128, 4 waves 2x2, wave-tile 64x64 ===========
template<int BN, int ACT, bool BIAS, bool OUTBF>
__global__ __launch_bounds__(256) void gemm_mfma_k(
    const unsigned short* A0, long as0, int K0, int dv0,
    const unsigned short* A1, long as1, int K1, int dv1,
    const unsigned short* A2, long as2, int K2, int dv2,
    const unsigned short* Bt, long bs, int Ktot,
    const float* bias, long biass,
    void* Cv, long cs, int N) {
  constexpr int TN = BN / 32;
  __shared__ unsigned short As[128 * 40];
  __shared__ unsigned short Bs[BN * 40];
  int tid = threadIdx.x;
  int mp = blockIdx.z;
  int n0 = blockIdx.x * BN, m0 = blockIdx.y * 128;
  const unsigned short* Bp = Bt + (long)mp * bs;

  f32x4 acc[4][TN];
#pragma unroll
  for (int i = 0; i < 4; ++i)
#pragma unroll
    for (int j = 0; j < TN; ++j) acc[i][j] = (f32x4){0.f, 0.f, 0.f, 0.f};

  const unsigned short* Asg[3] = {A0 + (long)mp * as0, A1 + (long)mp * as1,
                                  A2 + (long)mp * as2};
  const int Ksg[3] = {K0, K1, K2};
  const int Dsg[3] = {dv0, dv1, dv2};

  int wave = tid >> 6, lane = tid & 63;
  int wm = wave >> 1, wn = wave & 1;
  int quad = lane >> 4, r16 = lane & 15;

  int kbase = 0;
  for (int sg = 0; sg < 3; ++sg) {
    const unsigned short* A = Asg[sg];
    int K = Ksg[sg], dv = Dsg[sg];
    for (int k0 = 0; k0 < K; k0 += 32) {
      {
        int row = tid >> 1, half = tid & 1;
        int gr = m0 + row;
        int ar = (dv > 1) ? (gr / dv) : gr;
        const unsigned short* p = A + (long)ar * K + k0 + half * 16;
        uint4 v0 = *(const uint4*)p;
        uint4 v1 = *(const uint4*)(p + 8);
        int off = row * 40 + half * 16;
        *(uint4*)&As[off] = v0;
        *(uint4*)&As[off + 8] = v1;
      }
      {
        int col = tid >> 1, half = tid & 1;
        const unsigned short* p = Bp + (long)(n0 + col) * Ktot + kbase + k0 + half * 16;
        uint4 b0 = *(const uint4*)p;
        uint4 b1 = *(const uint4*)(p + 8);
        int off = col * 40 + half * 16;
        *(uint4*)&Bs[off] = b0;
        *(uint4*)&Bs[off + 8] = b1;
      }
      __syncthreads();
      bf16x8 af[4];
#pragma unroll
      for (int i = 0; i < 4; ++i)
        af[i] = *(const bf16x8*)&As[(wm * 64 + i * 16 + r16) * 40 + quad * 8];
      bf16x8 bfr[TN];
#pragma unroll
      for (int j = 0; j < TN; ++j)
        bfr[j] = *(const bf16x8*)&Bs[(wn * (BN / 2) + j * 16 + r16) * 40 + quad * 8];
#pragma unroll
      for (int i = 0; i < 4; ++i)
#pragma unroll
        for (int j = 0; j < TN; ++j)
          acc[i][j] = __builtin_amdgcn_mfma_f32_16x16x32_bf16(af[i], bfr[j], acc[i][j], 0, 0, 0);
      __syncthreads();
    }
    kbase += K;
  }
#pragma unroll
  for (int i = 0; i < 4; ++i) {
#pragma unroll
    for (int j = 0; j < TN; ++j) {
#pragma unroll
      for (int r = 0; r < 4; ++r) {
        int row = m0 + wm * 64 + i * 16 + quad * 4 + r;
        int col = n0 + wn * (BN / 2) + j * 16 + r16;
        float v = acc[i][j][r];
        if (BIAS) v += bias[mp * biass + col];
        if (ACT == 1) v = fmaxf(v, 0.f);
        if (ACT == 2) v = tanhf(v);
        if (OUTBF)
          ((unsigned short*)Cv)[(long)mp * cs + (long)row * N + col] = f2bf(v);
        else
          ((float*)Cv)[(long)mp * cs + (long)row * N + col] = v;
      }
    }
  }
}

// ====== GEMM2: BM=64, BN=64, 4 waves 2x2, wave-tile 32x32 (tanh+bias) =======
__global__ __launch_bounds__(256) void gemm_mfma64_k(
    const unsigned short* A0, long as0, int K0, int dv0,
    const unsigned short* A1, long as1, int K1, int dv1,
    const unsigned short* A2, long as2, int K2, int dv2,
    const unsigned short* Bt, long bs, int Ktot,
    const float* bias, long biass,
    unsigned short* C, long cs, int N) {
  __shared__ unsigned short As[64 * 40];
  __shared__ unsigned short Bs[64 * 40];
  int tid = threadIdx.x;
  int mp = blockIdx.z;
  int m0 = blockIdx.y * 64;
  const unsigned short* Bp = Bt + (long)mp * bs;

  f32x4 acc[2][2];
#pragma unroll
  for (int i = 0; i < 2; ++i)
#pragma unroll
    for (int j = 0; j < 2; ++j) acc[i][j] = (f32x4){0.f, 0.f, 0.f, 0.f};

  const unsigned short* Asg[3] = {A0 + (long)mp * as0, A1 + (long)mp * as1,
                                  A2 + (long)mp * as2};
  const int Ksg[3] = {K0, K1, K2};
  const int Dsg[3] = {dv0, dv1, dv2};

  int wave = tid >> 6, lane = tid & 63;
  int wm = wave >> 1, wn = wave & 1;
  int quad = lane >> 4, r16 = lane & 15;
  int row = tid >> 2, q = tid & 3;

  int kbase = 0;
  for (int sg = 0; sg < 3; ++sg) {
    const unsigned short* A = Asg[sg];
    int K = Ksg[sg], dv = Dsg[sg];
    for (int k0 = 0; k0 < K; k0 += 32) {
      {
        int gr = m0 + row;
        int ar = (dv > 1) ? (gr / dv) : gr;
        *(uint4*)&As[row * 40 + q * 8] =
            *(const uint4*)(A + (long)ar * K + k0 + q * 8);
      }
      *(uint4*)&Bs[row * 40 + q * 8] =
          *(const uint4*)(Bp + (long)row * Ktot + kbase + k0 + q * 8);
      __syncthreads();
      bf16x8 af[2], bfr[2];
#pragma unroll
      for (int i = 0; i < 2; ++i)
        af[i] = *(const bf16x8*)&As[(wm * 32 + i * 16 + r16) * 40 + quad * 8];
#pragma unroll
      for (int j = 0; j < 2; ++j)
        bfr[j] = *(const bf16x8*)&Bs[(wn * 32 + j * 16 + r16) * 40 + quad * 8];
#pragma unroll
      for (int i = 0; i < 2; ++i)
#pragma unroll
        for (int j = 0; j < 2; ++j)
          acc[i][j] = __builtin_amdgcn_mfma_f32_16x16x32_bf16(af[i], bfr[j], acc[i][j], 0, 0, 0);
      __syncthreads();
    }
    kbase += K;
  }
#pragma unroll
  for (int i = 0; i < 2; ++i) {
#pragma unroll
    for (int j = 0; j < 2; ++j) {
#pragma unroll
      for (int r = 0; r < 4; ++r) {
        int rr = m0 + wm * 32 + i * 16 + quad * 4 + r;
        int cc = wn * 32 + j * 16 + r16;
        float v = tanhf(acc[i][j][r] + bias[mp * biass + cc]);
        C[(long)mp * cs + (long)rr * N + cc] = f2bf(v);
      }
    }
  }
}

// == GEMM3 (mean fused): osum = [h0 | mean10(h1) | mean10(enew)] @ Wt^T ======
// BM=64, BN=128, grid (2, 8, 2). A seg1/seg2 are on-the-fly means over 10
// contiguous rows. Output fp32.
__global__ __launch_bounds__(256) void gemm3_meanfused_k(
    const unsigned short* __restrict__ h01, const unsigned short* __restrict__ enew,
    const unsigned short* __restrict__ wt1, float* __restrict__ osum) {
  __shared__ unsigned short As[64 * 40];
  __shared__ unsigned short Bs[128 * 40];
  int tid = threadIdx.x;
  int mp = blockIdx.z;
  int n0 = blockIdx.x * 128, m0 = blockIdx.y * 64;
  const unsigned short* h0 = h01 + (long)mp * 5632 * 256;
  const unsigned short* h1 = h0 + 512 * 256;
  const unsigned short* en = enew + (long)mp * 5120 * 64;
  const unsigned short* Bp = wt1 + 147456 + (long)mp * 2 * 147456;

  f32x4 acc[2][4];
#pragma unroll
  for (int i = 0; i < 2; ++i)
#pragma unroll
    for (int j = 0; j < 4; ++j) acc[i][j] = (f32x4){0.f, 0.f, 0.f, 0.f};

  int wave = tid >> 6, lane = tid & 63;
  int wm = wave >> 1, wn = wave & 1;
  int quad = lane >> 4, r16 = lane & 15;
  int row = tid >> 2, q = tid & 3;
  int gr = m0 + row;

  for (int it = 0; it < 18; ++it) {
    // ---- A stage
    {
      uint4 w;
      if (it < 8) {                 // seg0: h0 direct, k0 = it*32
        w = *(const uint4*)(h0 + (long)gr * 256 + it * 32 + q * 8);
      } else {
        const unsigned short* tb; int K, k0;
        if (it < 16) { tb = h1; K = 256; k0 = (it - 8) * 32; }
        else         { tb = en; K = 64;  k0 = (it - 16) * 32; }
        float s[8];
#pragma unroll
        for (int x = 0; x < 8; ++x) s[x] = 0.f;
        for (int ss = 0; ss < NS; ++ss) {
          const unsigned short* p = tb + (long)(gr * NS + ss) * K + k0 + q * 8;
          uint4 v = *(const uint4*)p;
          unsigned vals[4] = {v.x, v.y, v.z, v.w};
#pragma unroll
          for (int x = 0; x < 4; ++x) {
            s[x * 2] += bf2f((unsigned short)(vals[x] & 0xFFFF));
            s[x * 2 + 1] += bf2f((unsigned short)(vals[x] >> 16));
          }
        }
        w.x = pk2(s[0] * 0.1f, s[1] * 0.1f);
        w.y = pk2(s[2] * 0.1f, s[3] * 0.1f);
        w.z = pk2(s[4] * 0.1f, s[5] * 0.1f);
        w.w = pk2(s[6] * 0.1f, s[7] * 0.1f);
      }
      *(uint4*)&As[row * 40 + q * 8] = w;
    }
    // ---- B stage: 128 cols x 32 k, packed [col][576], k = it*32
    {
      int col = tid >> 1, half = tid & 1;
      const unsigned short* p = Bp + (long)(n0 + col) * 576 + it * 32 + half * 16;
      uint4 b0 = *(const uint4*)p;
      uint4 b1 = *(const uint4*)(p + 8);
      int off = col * 40 + half * 16;
      *(uint4*)&Bs[off] = b0;
      *(uint4*)&Bs[off + 8] = b1;
    }
    __syncthreads();
    bf16x8 af[2], bfr[4];
#pragma unroll
    for (int i = 0; i < 2; ++i)
      af[i] = *(const bf16x8*)&As[(wm * 32 + i * 16 + r16) * 40 + quad * 8];
#pragma unroll
    for (int j = 0; j < 4; ++j)
      bfr[j] = *(const bf16x8*)&Bs[(wn * 64 + j * 16 + r16) * 40 + quad * 8];
#pragma unroll
    for (int i = 0; i < 2; ++i)
#pragma unroll
      for (int j = 0; j < 4; ++j)
        acc[i][j] = __builtin_amdgcn_mfma_f32_16x16x32_bf16(af[i], bfr[j], acc[i][j], 0, 0, 0);
    __syncthreads();
  }
#pragma unroll
  for (int i = 0; i < 2; ++i) {
#pragma unroll
    for (int j = 0; j < 4; ++j) {
#pragma unroll
      for (int r = 0; r < 4; ++r) {
        int rr = m0 + wm * 32 + i * 16 + quad * 4 + r;
        int cc = n0 + wn * 64 + j * 16 + r16;
        osum[(long)mp * 131072 + (long)rr * 256 + cc] = acc[i][j][r];
      }
    }
  }
}

// ---- finalize: out = normalize((o0+o1)/2) @ fc_w + fc_b, f32 out ----
__global__ __launch_bounds__(64) void finalize_k(
    const float* __restrict__ o0, const float* __restrict__ o1,
    const float* __restrict__ fcw, const float* __restrict__ fcb,
    float* __restrict__ out) {
  int b = blockIdx.x, l = threadIdx.x;
  float v[4];
  float ss = 0.f;
#pragma unroll
  for (int k = 0; k < 4; ++k) {
    int j = l + 64 * k;
    v[k] = 0.5f * (o0[(long)b * 256 + j] + o1[(long)b * 256 + j]);
    ss += v[k] * v[k];
  }
#pragma unroll
  for (int off = 32; off > 0; off >>= 1) ss += __shfl_down(ss, off);
  ss = __shfl(ss, 0);
  float sc = 1.f / fmaxf(sqrtf(ss), 1e-12f);
  float p[8];
#pragma unroll
  for (int c = 0; c < 8; ++c) p[c] = 0.f;
#pragma unroll
  for (int k = 0; k < 4; ++k) {
    int j = l + 64 * k;
    float vh = v[k] * sc;
#pragma unroll
    for (int c = 0; c < 8; ++c) p[c] += vh * fcw[j * 8 + c];
  }
#pragma unroll
  for (int off = 32; off > 0; off >>= 1) {
#pragma unroll
    for (int c = 0; c < 8; ++c) p[c] += __shfl_down(p[c], off);
  }
  if (l == 0) {
#pragma unroll
    for (int c = 0; c < 8; ++c) out[b * 8 + c] = p[c] + fcb[c];
  }
}

extern "C" void kernel_launch(void* const* d_in, const int* in_sizes, int n_in,
                              void* d_out, int out_size, void* d_ws, size_t ws_size,
                              hipStream_t stream) {
  const int* ids = (const int*)d_in[0];
  const float* feats = (const float*)d_in[1];
  const int* n0i[2] = {(const int*)d_in[2], (const int*)d_in[4]};
  const int* n1i[2] = {(const int*)d_in[3], (const int*)d_in[5]};
  const int* e0i[2] = {(const int*)d_in[6], (const int*)d_in[8]};
  const int* e1i[2] = {(const int*)d_in[7], (const int*)d_in[9]};
  const float* emb[2] = {(const float*)d_in[10], (const float*)d_in[11]};
  const float* Wself = (const float*)d_in[12];
  const float* Wneigh = (const float*)d_in[13];
  const float* Wedg = (const float*)d_in[14];
  const float* Wec = (const float*)d_in[15];
  const float* bec = (const float*)d_in[16];
  const float* fcw = (const float*)d_in[17];
  const float* fcb = (const float*)d_in[18];
  float* out = (float*)d_out;

  // ---- workspace ----
  float* osum = (float*)d_ws;                               // [2][512][256] f32
  unsigned short* A1b  = (unsigned short*)(osum + 262144);  // [2][5632][576]
  unsigned short* eg0  = A1b + 6488064;                     // [2][5120][64]
  unsigned short* h01  = eg0 + 655360;                      // [2][5632][256]
  unsigned short* enew = h01 + 2883584;                     // [2][5120][64]
  unsigned short* wt1  = enew + 655360;                     // [4][256][576]
  unsigned short* wte  = wt1 + 589824;                      // [2][64][576]

  // 1) prep: weight pack + all 14 gathers
  {
    GJobs gj; int blk = 0, nj = 0;
    auto add = [&](const float* table, const int* idx, unsigned short* o,
                   int M, int D4, int ns, int ostride, float inv) {
      gj.j[nj] = {table, idx, o, M, D4, ns, ostride, blk, inv};
      blk += (M * D4) / 256; ++nj;
    };
    for (int mp = 0; mp < 2; ++mp) {
      unsigned short* Am = A1b + (size_t)mp * 5632 * 576;
      add(feats, ids,     Am,                     512, 64, 1, 576, 1.0f);
      add(feats, n0i[mp], Am + 512 * 576,         5120, 64, 1, 576, 1.0f);
      add(feats, n0i[mp], Am + 256,               512, 64, NS, 576, 0.1f);
      add(feats, n1i[mp], Am + 512 * 576 + 256,   5120, 64, NS, 576, 0.1f);
      add(emb[mp], e0i[mp], Am + 512,             512, 16, NS, 576, 0.1f);
      add(emb[mp], e1i[mp], Am + 512 * 576 + 512, 5120, 16, NS, 576, 0.1f);
      add(emb[mp], e0i[mp], eg0 + (size_t)mp * 327680, 5120, 16, 1, 64, 1.0f);
    }
    gprep_k<<<dim3(PACKB + blk), dim3(256), 0, stream>>>(
        gj, nj, Wself, Wneigh, Wedg, Wec, wt1, wte);
  }

  // 2) layer-0 agg: h01 = relu(A1 @ WT1[mp][0])  [2][5632][256] bf16
  gemm_mfma_k<128, 1, false, true><<<dim3(2, 44, 2), dim3(256), 0, stream>>>(
      A1b, 5632L * 576, 576, 1, A1b, 0, 0, 1, A1b, 0, 0, 1,
      wt1, 2L * 147456, 576, nullptr, 0, h01, 5632L * 256, 256);

  // 3) edge update: enew = tanh([h0(rep10) | h1 | eg0] @ WTe + be) [2][5120][64]
  gemm_mfma64_k<<<dim3(1, 80, 2), dim3(256), 0, stream>>>(
      h01, 5632L * 256, 256, 10, h01 + 512 * 256, 5632L * 256, 256, 1,
      eg0, 5120L * 64, 64, 1,
      wte, 36864L, 576, bec, 128, enew, 5120L * 64, 64);

  // 4) layer-1 agg with fused means: osum [2][512][256] f32
  gemm3_meanfused_k<<<dim3(2, 8, 2), dim3(256), 0, stream>>>(h01, enew, wt1, osum);

  // 5) metapath mean + L2 normalize + FC
  finalize_k<<<dim3(512), dim3(64), 0, stream>>>(osum, osum + 131072, fcw, fcb, out);
}